// Round 21
// baseline (213.021 us; speedup 1.0000x reference)
//
#include <hip/hip_runtime.h>
#include <math.h>

// Problem constants (match reference)
#define NT_     64000
#define E_      400000
#define B_      128
#define L_      50
#define KD_     256     // K*D
#define D_      64
#define N_USER_ 100000
#define MAXN_   (B_*L_ + B_)   // 6528 max distinct head nodes
#define CAP_    48             // per-node slot capacity; P(Poisson(6.25) > 48) ~ 1e-30

// MEASUREMENT ROUND: head_fused made idempotent (atomicAdd -> inc[bl][k] writes),
// dispatched x4. dur = base + 3*H. Branches pre-committed in the journal.

// ---------------- wave helpers ----------------
__device__ __forceinline__ float wred(float v){
#pragma unroll
  for(int s=32;s;s>>=1) v += __shfl_xor(v, s, 64);
  return v;
}

// ---------------- threefry2x32 (JAX key(1) == (0,1)), partitionable XOR-fold ----------------
__device__ __forceinline__ unsigned rotl(unsigned x, int r){ return (x<<r)|(x>>(32-r)); }

__device__ void tf2x32(unsigned c0, unsigned c1, unsigned &o0, unsigned &o1){
  const unsigned k0=0u, k1=1u;
  const unsigned k2=k0^k1^0x1BD11BDAu;
  unsigned x0=c0+k0, x1=c1+k1;
  const int RA[4]={13,15,26,6};
  const int RB[4]={17,29,16,24};
#pragma unroll
  for(int i=0;i<4;i++){ x0+=x1; x1=rotl(x1,RA[i]); x1^=x0; }
  x0+=k1; x1+=k2+1u;
#pragma unroll
  for(int i=0;i<4;i++){ x0+=x1; x1=rotl(x1,RB[i]); x1^=x0; }
  x0+=k2; x1+=k0+2u;
#pragma unroll
  for(int i=0;i<4;i++){ x0+=x1; x1=rotl(x1,RA[i]); x1^=x0; }
  x0+=k0; x1+=k1+3u;
#pragma unroll
  for(int i=0;i<4;i++){ x0+=x1; x1=rotl(x1,RB[i]); x1^=x0; }
  x0+=k1; x1+=k2+4u;
#pragma unroll
  for(int i=0;i<4;i++){ x0+=x1; x1=rotl(x1,RA[i]); x1^=x0; }
  x0+=k2; x1+=k0+5u;
  o0=x0; o1=x1;
}

__device__ float gumbel_at(int idx){
  unsigned o0,o1;
  tf2x32(0u, (unsigned)idx, o0, o1);      // counts uint64 iota: hi=0, lo=idx
  unsigned bits = o0 ^ o1;                 // 32-bit XOR fold (partitionable)
  unsigned fb = (bits>>9) | 0x3f800000u;   // [1,2)
  float f = __uint_as_float(fb) - 1.0f;    // [0,1)
  const float mn=1e-4f, mx=1.0f-1e-4f;
  float u = fmaxf(mn, f*(mx-mn)+mn);
  return -logf(-logf(u));
}

// ---------------- K1: head-node dedup + slot-CSR fill (single pass over E) ----------------
// markpos encoding: 0 = unassigned, s+1 = slot s (zero-memset friendly)
__global__ void fill_all(const int* __restrict__ seq_map, const int* __restrict__ tar_map,
                         const int* __restrict__ row, const int* __restrict__ col,
                         const int* __restrict__ node_ids,
                         int* __restrict__ markpos, int* __restrict__ nlist,
                         int* __restrict__ ncount, int* __restrict__ need,
                         int* __restrict__ cnt, int2* __restrict__ pk2){
  int i = blockIdx.x*256 + threadIdx.x;
  if(i < MAXN_){
    int n = (i < B_*L_) ? seq_map[i] : tar_map[i - B_*L_];
    int old = atomicCAS(&markpos[n], 0, -1);
    if(old == 0){
      int s = atomicAdd(ncount, 1);
      nlist[s] = n;
      need[n] = 1;
      markpos[n] = s + 1;
    }
  }
  if(i < E_){
    int c = col[i], r = row[i];
    int j = atomicAdd(&cnt[c], 1);
    if(j < CAP_) pk2[c*CAP_ + j] = make_int2(node_ids[r], r);
  }
}

// ---------------- K2: prep — need prop + W transposes + prefolded edge weights ----------------
__global__ void prep_all(const int* __restrict__ cnt, const int2* __restrict__ pk2,
                         const int* __restrict__ nlist, const int* __restrict__ ncount,
                         const float* __restrict__ W1, const float* __restrict__ W2,
                         int* __restrict__ need, float* __restrict__ W1T,
                         float* __restrict__ W2T, float* __restrict__ wgt){
  const int NB_NEED = (MAXN_+255)/256;    // 26
  int b = blockIdx.x, t = threadIdx.x;
  if(b < NB_NEED){
    int s = b*256 + t;
    if(s < *ncount){
      int c = nlist[s];
      int d = cnt[c]; if(d > CAP_) d = CAP_;
      int base = c*CAP_;
      for(int j=0;j<d;j++) need[pk2[base+j].y] = 1;   // x1[r] read by conv2
    }
  } else if(b < NB_NEED + 32){
    int tb = b - NB_NEED;
    int idx = (tb & 15)*256 + t;         // 0..4095
    int e = idx >> 6, d = idx & 63;
    if(tb < 16) W1T[d*64 + e] = W1[e*64 + d];
    else        W2T[d*64 + e] = W2[e*64 + d];
  } else {
    int c = (b - NB_NEED - 32)*256 + t;  // one thread per node
    int d = cnt[c]; if(d > CAP_) d = CAP_;
    if(d > 0){
      float dc = (1.0f/sqrtf((float)cnt[c]))*0.25f;
      int base = c*CAP_;
      for(int j=0;j<d;j++){
        int r = pk2[base+j].y;
        int cr = cnt[r];
        float dr = (cr>0) ? (1.0f/sqrtf((float)cr)) : 0.0f;
        wgt[base+j] = dr*dc;
      }
    }
  }
}

// ---------------- K3: conv1 (filtered): wave-per-node, sequential pk2/wgt streams ----------------
__global__ void aggregate1(const float4* __restrict__ embed4, const int* __restrict__ cnt,
                           const int2* __restrict__ pk2, const float* __restrict__ wgt,
                           const int* __restrict__ need, float4* __restrict__ x14){
  int wv = threadIdx.x>>6, lane = threadIdx.x&63;
  int c = blockIdx.x*4 + wv;
  if(!need[c]) return;                    // x1[c] never read downstream
  int deg = cnt[c]; if(deg > CAP_) deg = CAP_;
  int base = c*CAP_;
  float4 acc = {0.f,0.f,0.f,0.f};
  for(int i=0; i<deg; i+=8){
    int idx[8]; float w[8];
#pragma unroll
    for(int j=0;j<8;j++){
      bool ok = (i+j) < deg;
      int s = ok ? (base+i+j) : base;
      idx[j] = pk2[s].x;
      w[j]   = ok ? wgt[s] : 0.f;
    }
#pragma unroll
    for(int j=0;j<8;j++){
      float4 v = embed4[(size_t)idx[j]*64 + lane];
      acc.x = fmaf(v.x, w[j], acc.x);
      acc.y = fmaf(v.y, w[j], acc.y);
      acc.z = fmaf(v.z, w[j], acc.z);
      acc.w = fmaf(v.w, w[j], acc.w);
    }
  }
  x14[(size_t)c*64+lane] = acc;
}

// ---------------- K4: conv2 fused — hoisted loads, softmax once/edge, 2 syncs/batch ----------------
__global__ void conv2_fused(const float* __restrict__ x1, const int* __restrict__ cnt,
                            const int2* __restrict__ pk2, const float* __restrict__ wgt,
                            const int* __restrict__ nlist, const int* __restrict__ ncount,
                            float* __restrict__ x2c){
  int slot = blockIdx.x;
  if(slot >= *ncount) return;
  int c = nlist[slot];
  int t = threadIdx.x, k = t>>6, lane = t&63;
  float tx = tanhf(x1[(size_t)c*KD_ + t]);
  float acc = 0.f;
  __shared__ float zs[8][4];
  __shared__ float ws[8][4];
  int deg = cnt[c]; if(deg > CAP_) deg = CAP_;
  int base = c*CAP_;
  for(int i0=0; i0<deg; i0+=8){
    int nb = deg - i0; nb = (nb>8)?8:nb;  // block-uniform
    float xr8[8];
    for(int j=0;j<nb;j++)
      xr8[j] = x1[(size_t)pk2[base+i0+j].y*KD_ + t];
    for(int j=0;j<nb;j++){
      float zk = wred(xr8[j]*tx);         // z[e,k] = dot(x1[row,k,:], tanh(x1[col,k,:]))
      if(lane==0) zs[j][k] = zk;
    }
    __syncthreads();
    if(t < nb){
      float z0=zs[t][0], z1=zs[t][1], z2=zs[t][2], z3=zs[t][3];
      float m = fmaxf(fmaxf(z0,z1), fmaxf(z2,z3));
      float e0=expf(z0-m), e1=expf(z1-m), e2=expf(z2-m), e3=expf(z3-m);
      float inv = (4.f*wgt[base+i0+t])/(e0+e1+e2+e3);   // base_e = 4*wgt
      ws[t][0]=e0*inv; ws[t][1]=e1*inv; ws[t][2]=e2*inv; ws[t][3]=e3*inv;
    }
    __syncthreads();
    for(int j=0;j<nb;j++)
      acc = fmaf(xr8[j], ws[j][k], acc);
  }
  x2c[(size_t)slot*KD_ + t] = acc;
}

// ---------------- K5: head — IDEMPOTENT: writes inc[bl][k] (no atomics) ----------------
__global__ void head_fused(const float* __restrict__ embed, const float* __restrict__ x2c,
                           const int* __restrict__ markpos,
                           const float* __restrict__ W1T, const float* __restrict__ W2T,
                           const int* __restrict__ node_ids, const int* __restrict__ seq_map,
                           const int* __restrict__ tar_map, const int* __restrict__ seq_idx,
                           const int* __restrict__ seq_len,
                           const int* __restrict__ uid, const int* __restrict__ sid,
                           const float* __restrict__ seqs_time, const float* __restrict__ clk_time,
                           const float* __restrict__ tau_p, const float* __restrict__ delta,
                           float* __restrict__ mu, float* __restrict__ inc){
  int bl = blockIdx.x;
  int b = bl / L_, l = bl % L_;
  if(l >= seq_len[b]) return;           // masked position: inc stays 0 (memset)
  int t = threadIdx.x, k = t>>6, lane = t&63;
  __shared__ float sxt[KD_], sxv[KD_];
  int n = seq_map[bl];
  sxt[t] = x2c[(size_t)(markpos[tar_map[b]]-1)*KD_ + t];
  sxv[t] = x2c[(size_t)(markpos[n]-1)*KD_ + t];
  __syncthreads();
  float av = embed[((size_t)(N_USER_ + sid[b]))*KD_ + t];
  float se = embed[(size_t)node_ids[n]*KD_ + t];
  const float* xt_k = sxt + k*64;
  const float* xv_k = sxv + k*64;
#pragma unroll 8
  for(int d=0; d<64; d++){
    av = fmaf(xt_k[d], W2T[d*64 + lane], av);
    se = fmaf(xv_k[d], W1T[d*64 + lane], se);
  }
  float au = embed[(size_t)uid[b]*KD_ + t];
  float nv  = wred(av*av);
  float nu  = wred(au*au);
  float duv = wred(av*au);
  float dv  = wred(se*av);
  float du  = wred(se*au);
  float ns  = wred(se*se);
  __shared__ float s6[6][4];
  if(lane==0){ s6[0][k]=nv; s6[1][k]=nu; s6[2][k]=duv; s6[3][k]=dv; s6[4][k]=du; s6[5][k]=ns; }
  __syncthreads();
  if(t==0){
    float jv  = expf(-(clk_time[b]-seqs_time[bl]) * (1.0f/1000.0f) * delta[uid[b]]);
    float tau = tau_p[seq_idx[bl]];
    float gam[4], lg[4];
    float m = -1e30f;
#pragma unroll
    for(int kk=0;kk<4;kk++){
      float rnv = fmaxf(sqrtf(s6[0][kk]), 1e-8f);
      float rnu = fmaxf(sqrtf(s6[1][kk]), 1e-8f);
      float ins = 1.f/fmaxf(sqrtf(s6[5][kk]), 1e-8f);
      if(l==0) mu[b*4+kk] = s6[2][kk]/(rnv*rnu);
      gam[kk] = s6[3][kk]*ins/rnv;
      float logit = s6[4][kk]*ins/rnu;
      lg[kk] = (logit + gumbel_at(bl*4+kk))/tau;
      m = fmaxf(m, lg[kk]);
    }
    float es[4], ssum=0.f;
#pragma unroll
    for(int kk=0;kk<4;kk++){ es[kk]=expf(lg[kk]-m); ssum+=es[kk]; }
    float isum = 1.f/ssum;
#pragma unroll
    for(int kk=0;kk<4;kk++)
      inc[bl*4+kk] = jv * gam[kk] * es[kk]*isum;   // direct write (idempotent)
  }
}

// ---------------- K6: finalize — sums inc over l ----------------
__global__ void finalize(const float* __restrict__ mu, const float* __restrict__ inc,
                         float* __restrict__ out){
  int b = threadIdx.x;
  if(b < B_){
    float s = 0.f;
#pragma unroll
    for(int k=0;k<4;k++) s += mu[b*4+k];
    for(int l=0;l<L_;l++){
      const float* p = inc + (b*L_+l)*4;
      s += p[0]+p[1]+p[2]+p[3];
    }
    out[b] = s * 0.25f;
  }
}

// ---------------- launch ----------------
extern "C" void kernel_launch(void* const* d_in, const int* in_sizes, int n_in,
                              void* d_out, int out_size, void* d_ws, size_t ws_size,
                              hipStream_t stream){
  const float* embed = (const float*)d_in[0];
  const float* delta = (const float*)d_in[1];
  const float* tau_p = (const float*)d_in[2];
  const float* W1    = (const float*)d_in[3];
  const float* W2    = (const float*)d_in[4];
  const float* seqs_time = (const float*)d_in[5];
  const float* clk_time  = (const float*)d_in[6];
  const int* uid      = (const int*)d_in[7];
  const int* sid      = (const int*)d_in[8];
  const int* node_ids = (const int*)d_in[9];
  const int* edge_index = (const int*)d_in[10];
  const int* seq_map  = (const int*)d_in[11];
  const int* tar_map  = (const int*)d_in[12];
  const int* seq_idx  = (const int*)d_in[13];
  const int* seq_len  = (const int*)d_in[14];
  const int* row = edge_index;
  const int* col = edge_index + E_;
  float* out = (float*)d_out;

  // carve: ONE contiguous zero-init region first (inc,ncount,cnt,need,markpos)
  char* wp = (char*)d_ws;
  size_t o = 0;
  auto carve = [&](size_t bytes)->char*{ char* r = wp + o; o = (o + bytes + 255) & ~(size_t)255; return r; };
  float* inc     = (float*)carve((size_t)B_*L_*4*4);   // 102 KB, zeroed each call
  int*   ncount  = (int*)  carve((size_t)4);
  int*   cnt     = (int*)  carve((size_t)NT_*4);
  int*   need    = (int*)  carve((size_t)NT_*4);
  int*   markpos = (int*)  carve((size_t)NT_*4);
  char*  zero_end = wp + o;
  float* mu      = (float*)carve((size_t)B_*4*4);
  int*   nlist   = (int*)  carve((size_t)MAXN_*4);
  float* W1T     = (float*)carve((size_t)64*64*4);
  float* W2T     = (float*)carve((size_t)64*64*4);
  int2*  pk2     = (int2*) carve((size_t)NT_*CAP_*8);   // ~24.6 MB slot CSR
  float* wgt     = (float*)carve((size_t)NT_*CAP_*4);   // ~12.3 MB prefolded weights
  float* x2c     = (float*)carve((size_t)MAXN_*KD_*4);
  float* x1      = (float*)carve((size_t)NT_*KD_*4);    // 64 MB

  hipMemsetAsync(inc, 0, (size_t)(zero_end - (char*)inc), stream);

  // K1: head-node dedup + slot-CSR fill (one pass over E)
  fill_all<<<(E_+255)/256, 256, 0, stream>>>(seq_map, tar_map, row, col, node_ids,
                                             markpos, nlist, ncount, need, cnt, pk2);
  // K2: need propagation + W transposes + prefolded edge weights
  prep_all<<<(MAXN_+255)/256 + 32 + NT_/256, 256, 0, stream>>>(cnt, pk2, nlist, ncount,
                                                               W1, W2, need, W1T, W2T, wgt);
  // K3: conv1, only for nodes whose x1 is read downstream
  aggregate1<<<NT_/4, 256, 0, stream>>>((const float4*)embed, cnt, pk2, wgt,
                                        need, (float4*)x1);
  // K4: conv2
  conv2_fused<<<MAXN_, 256, 0, stream>>>(x1, cnt, pk2, wgt, nlist, ncount, x2c);
  // K5: head — x4 (idempotent) to measure H = (dur - base)/3
  for(int rep=0; rep<4; ++rep)
    head_fused<<<B_*L_, 256, 0, stream>>>(embed, x2c, markpos, W1T, W2T,
                                          node_ids, seq_map, tar_map, seq_idx, seq_len,
                                          uid, sid, seqs_time, clk_time, tau_p, delta,
                                          mu, inc);
  // K6: finalize
  finalize<<<1, 128, 0, stream>>>(mu, inc, out);
}

// Round 22
// 137.769 us; speedup vs baseline: 1.5462x; 1.5462x over previous
//
#include <hip/hip_runtime.h>
#include <math.h>

// Problem constants (match reference)
#define NT_     64000
#define E_      400000
#define B_      128
#define L_      50
#define KD_     256     // K*D
#define D_      64
#define N_USER_ 100000
#define MAXN_   (B_*L_ + B_)   // 6528 max distinct head nodes
#define CAP_    48             // per-node slot capacity; P(Poisson(6.25) > 48) ~ 1e-30

// ---------------- wave helpers ----------------
__device__ __forceinline__ float wred(float v){
#pragma unroll
  for(int s=32;s;s>>=1) v += __shfl_xor(v, s, 64);
  return v;
}

// ---------------- threefry2x32 (JAX key(1) == (0,1)), partitionable XOR-fold ----------------
__device__ __forceinline__ unsigned rotl(unsigned x, int r){ return (x<<r)|(x>>(32-r)); }

__device__ void tf2x32(unsigned c0, unsigned c1, unsigned &o0, unsigned &o1){
  const unsigned k0=0u, k1=1u;
  const unsigned k2=k0^k1^0x1BD11BDAu;
  unsigned x0=c0+k0, x1=c1+k1;
  const int RA[4]={13,15,26,6};
  const int RB[4]={17,29,16,24};
#pragma unroll
  for(int i=0;i<4;i++){ x0+=x1; x1=rotl(x1,RA[i]); x1^=x0; }
  x0+=k1; x1+=k2+1u;
#pragma unroll
  for(int i=0;i<4;i++){ x0+=x1; x1=rotl(x1,RB[i]); x1^=x0; }
  x0+=k2; x1+=k0+2u;
#pragma unroll
  for(int i=0;i<4;i++){ x0+=x1; x1=rotl(x1,RA[i]); x1^=x0; }
  x0+=k0; x1+=k1+3u;
#pragma unroll
  for(int i=0;i<4;i++){ x0+=x1; x1=rotl(x1,RB[i]); x1^=x0; }
  x0+=k1; x1+=k2+4u;
#pragma unroll
  for(int i=0;i<4;i++){ x0+=x1; x1=rotl(x1,RA[i]); x1^=x0; }
  x0+=k2; x1+=k0+5u;
  o0=x0; o1=x1;
}

__device__ float gumbel_at(int idx){
  unsigned o0,o1;
  tf2x32(0u, (unsigned)idx, o0, o1);      // counts uint64 iota: hi=0, lo=idx
  unsigned bits = o0 ^ o1;                 // 32-bit XOR fold (partitionable)
  unsigned fb = (bits>>9) | 0x3f800000u;   // [1,2)
  float f = __uint_as_float(fb) - 1.0f;    // [0,1)
  const float mn=1e-4f, mx=1.0f-1e-4f;
  float u = fmaxf(mn, f*(mx-mn)+mn);
  return -logf(-logf(u));
}

// ---------------- K1: head-node dedup + slot-CSR fill (single pass over E) ----------------
// markpos encoding: 0 = unassigned, s+1 = slot s (zero-memset friendly)
__global__ void fill_all(const int* __restrict__ seq_map, const int* __restrict__ tar_map,
                         const int* __restrict__ row, const int* __restrict__ col,
                         const int* __restrict__ node_ids,
                         int* __restrict__ markpos, int* __restrict__ nlist,
                         int* __restrict__ ncount, int* __restrict__ need,
                         int* __restrict__ cnt, int2* __restrict__ pk2){
  int i = blockIdx.x*256 + threadIdx.x;
  if(i < MAXN_){
    int n = (i < B_*L_) ? seq_map[i] : tar_map[i - B_*L_];
    int old = atomicCAS(&markpos[n], 0, -1);
    if(old == 0){
      int s = atomicAdd(ncount, 1);
      nlist[s] = n;
      need[n] = 1;
      markpos[n] = s + 1;
    }
  }
  if(i < E_){
    int c = col[i], r = row[i];
    int j = atomicAdd(&cnt[c], 1);
    if(j < CAP_) pk2[c*CAP_ + j] = make_int2(node_ids[r], r);
  }
}

// ---------------- K2: prep — need prop + W transposes + prefolded edge weights ----------------
__global__ void prep_all(const int* __restrict__ cnt, const int2* __restrict__ pk2,
                         const int* __restrict__ nlist, const int* __restrict__ ncount,
                         const float* __restrict__ W1, const float* __restrict__ W2,
                         int* __restrict__ need, float* __restrict__ W1T,
                         float* __restrict__ W2T, float* __restrict__ wgt){
  const int NB_NEED = (MAXN_+255)/256;    // 26
  int b = blockIdx.x, t = threadIdx.x;
  if(b < NB_NEED){
    int s = b*256 + t;
    if(s < *ncount){
      int c = nlist[s];
      int d = cnt[c]; if(d > CAP_) d = CAP_;
      int base = c*CAP_;
      for(int j=0;j<d;j++) need[pk2[base+j].y] = 1;   // x1[r] read by conv2
    }
  } else if(b < NB_NEED + 32){
    int tb = b - NB_NEED;
    int idx = (tb & 15)*256 + t;         // 0..4095
    int e = idx >> 6, d = idx & 63;
    if(tb < 16) W1T[d*64 + e] = W1[e*64 + d];
    else        W2T[d*64 + e] = W2[e*64 + d];
  } else {
    int c = (b - NB_NEED - 32)*256 + t;  // one thread per node
    int d = cnt[c]; if(d > CAP_) d = CAP_;
    if(d > 0){
      float dc = (1.0f/sqrtf((float)cnt[c]))*0.25f;
      int base = c*CAP_;
      for(int j=0;j<d;j++){
        int r = pk2[base+j].y;
        int cr = cnt[r];
        float dr = (cr>0) ? (1.0f/sqrtf((float)cr)) : 0.0f;
        wgt[base+j] = dr*dc;
      }
    }
  }
}

// ---------------- K3: conv1 (filtered): wave-per-node, sequential pk2/wgt streams ----------------
__global__ void aggregate1(const float4* __restrict__ embed4, const int* __restrict__ cnt,
                           const int2* __restrict__ pk2, const float* __restrict__ wgt,
                           const int* __restrict__ need, float4* __restrict__ x14){
  int wv = threadIdx.x>>6, lane = threadIdx.x&63;
  int c = blockIdx.x*4 + wv;
  if(!need[c]) return;                    // x1[c] never read downstream
  int deg = cnt[c]; if(deg > CAP_) deg = CAP_;
  int base = c*CAP_;
  float4 acc = {0.f,0.f,0.f,0.f};
  for(int i=0; i<deg; i+=8){
    int idx[8]; float w[8];
#pragma unroll
    for(int j=0;j<8;j++){
      bool ok = (i+j) < deg;
      int s = ok ? (base+i+j) : base;
      idx[j] = pk2[s].x;
      w[j]   = ok ? wgt[s] : 0.f;
    }
#pragma unroll
    for(int j=0;j<8;j++){
      float4 v = embed4[(size_t)idx[j]*64 + lane];
      acc.x = fmaf(v.x, w[j], acc.x);
      acc.y = fmaf(v.y, w[j], acc.y);
      acc.z = fmaf(v.z, w[j], acc.z);
      acc.w = fmaf(v.w, w[j], acc.w);
    }
  }
  x14[(size_t)c*64+lane] = acc;
}

// ---------------- K4: conv2 fused — hoisted loads, softmax once/edge ----------------
__global__ void conv2_fused(const float* __restrict__ x1, const int* __restrict__ cnt,
                            const int2* __restrict__ pk2, const float* __restrict__ wgt,
                            const int* __restrict__ nlist, const int* __restrict__ ncount,
                            float* __restrict__ x2c){
  int slot = blockIdx.x;
  if(slot >= *ncount) return;
  int c = nlist[slot];
  int t = threadIdx.x, k = t>>6, lane = t&63;
  float tx = tanhf(x1[(size_t)c*KD_ + t]);
  float acc = 0.f;
  __shared__ float zs[8][4];
  __shared__ float ws[8][4];
  int deg = cnt[c]; if(deg > CAP_) deg = CAP_;
  int base = c*CAP_;
  for(int i0=0; i0<deg; i0+=8){
    int nb = deg - i0; nb = (nb>8)?8:nb;  // block-uniform
    float xr8[8];
    for(int j=0;j<nb;j++)
      xr8[j] = x1[(size_t)pk2[base+i0+j].y*KD_ + t];
    for(int j=0;j<nb;j++){
      float zk = wred(xr8[j]*tx);         // z[e,k] = dot(x1[row,k,:], tanh(x1[col,k,:]))
      if(lane==0) zs[j][k] = zk;
    }
    __syncthreads();
    if(t < nb){
      float z0=zs[t][0], z1=zs[t][1], z2=zs[t][2], z3=zs[t][3];
      float m = fmaxf(fmaxf(z0,z1), fmaxf(z2,z3));
      float e0=expf(z0-m), e1=expf(z1-m), e2=expf(z2-m), e3=expf(z3-m);
      float inv = (4.f*wgt[base+i0+t])/(e0+e1+e2+e3);   // base_e = 4*wgt
      ws[t][0]=e0*inv; ws[t][1]=e1*inv; ws[t][2]=e2*inv; ws[t][3]=e3*inv;
    }
    __syncthreads();
    for(int j=0;j<nb;j++)
      acc = fmaf(xr8[j], ws[j][k], acc);
  }
  x2c[(size_t)slot*KD_ + t] = acc;
}

// ---------------- K5: prep_av — per-b a_v matvec + norms + mu (was 25x redundant in head) ----------------
__global__ void prep_av(const float* __restrict__ embed, const float* __restrict__ x2c,
                        const int* __restrict__ markpos, const float* __restrict__ W2T,
                        const int* __restrict__ uid, const int* __restrict__ sid,
                        const int* __restrict__ tar_map,
                        float* __restrict__ a_v, float* __restrict__ mu,
                        float* __restrict__ sc){
  int b = blockIdx.x;
  int t = threadIdx.x, k = t>>6, lane = t&63;
  __shared__ float sxt[KD_];
  sxt[t] = x2c[(size_t)(markpos[tar_map[b]]-1)*KD_ + t];
  __syncthreads();
  float av = embed[((size_t)(N_USER_ + sid[b]))*KD_ + t];
  const float* xt_k = sxt + k*64;
#pragma unroll 8
  for(int d=0; d<64; d++)
    av = fmaf(xt_k[d], W2T[d*64 + lane], av);
  float au = embed[(size_t)uid[b]*KD_ + t];
  float nv  = wred(av*av);
  float nu  = wred(au*au);
  float duv = wred(av*au);
  a_v[(size_t)b*KD_ + t] = av;
  if(lane==0){
    float rnv = fmaxf(sqrtf(nv), 1e-8f);
    float rnu = fmaxf(sqrtf(nu), 1e-8f);
    mu[b*4+k]      = duv/(rnv*rnu);
    sc[(b*4+k)*2+0] = 1.f/rnv;
    sc[(b*4+k)*2+1] = 1.f/rnu;
  }
}

// ---------------- K6: head — se matvec only; av/scalars precomputed ----------------
__global__ void head_fused(const float* __restrict__ embed, const float* __restrict__ x2c,
                           const int* __restrict__ markpos, const float* __restrict__ a_v,
                           const float* __restrict__ sc, const float* __restrict__ W1T,
                           const int* __restrict__ node_ids, const int* __restrict__ seq_map,
                           const int* __restrict__ seq_idx, const int* __restrict__ seq_len,
                           const int* __restrict__ uid,
                           const float* __restrict__ seqs_time, const float* __restrict__ clk_time,
                           const float* __restrict__ tau_p, const float* __restrict__ delta,
                           float* __restrict__ inc){
  int bl = blockIdx.x;
  int b = bl / L_, l = bl % L_;
  if(l >= seq_len[b]) return;           // masked position: inc stays 0 (memset)
  int t = threadIdx.x, k = t>>6, lane = t&63;
  __shared__ float sxv[KD_];
  int n = seq_map[bl];
  sxv[t] = x2c[(size_t)(markpos[n]-1)*KD_ + t];
  __syncthreads();
  float se = embed[(size_t)node_ids[n]*KD_ + t];
  const float* xv_k = sxv + k*64;
#pragma unroll 8
  for(int d=0; d<64; d++)
    se = fmaf(xv_k[d], W1T[d*64 + lane], se);
  float av = a_v[(size_t)b*KD_ + t];
  float au = embed[(size_t)uid[b]*KD_ + t];
  float dv  = wred(se*av);
  float du  = wred(se*au);
  float ns  = wred(se*se);
  __shared__ float s3[3][4];
  if(lane==0){ s3[0][k]=dv; s3[1][k]=du; s3[2][k]=ns; }
  __syncthreads();
  if(t==0){
    float jv  = expf(-(clk_time[b]-seqs_time[bl]) * (1.0f/1000.0f) * delta[uid[b]]);
    float tau = tau_p[seq_idx[bl]];
    float gam[4], lg[4];
    float m = -1e30f;
#pragma unroll
    for(int kk=0;kk<4;kk++){
      float ins = 1.f/fmaxf(sqrtf(s3[2][kk]), 1e-8f);
      gam[kk] = s3[0][kk]*ins*sc[(b*4+kk)*2+0];
      float logit = s3[1][kk]*ins*sc[(b*4+kk)*2+1];
      lg[kk] = (logit + gumbel_at(bl*4+kk))/tau;
      m = fmaxf(m, lg[kk]);
    }
    float es[4], ssum=0.f;
#pragma unroll
    for(int kk=0;kk<4;kk++){ es[kk]=expf(lg[kk]-m); ssum+=es[kk]; }
    float isum = 1.f/ssum;
#pragma unroll
    for(int kk=0;kk<4;kk++)
      inc[bl*4+kk] = jv * gam[kk] * es[kk]*isum;   // direct write (idempotent)
  }
}

// ---------------- K7: finalize — sums inc over l ----------------
__global__ void finalize(const float* __restrict__ mu, const float* __restrict__ inc,
                         float* __restrict__ out){
  int b = threadIdx.x;
  if(b < B_){
    float s = 0.f;
#pragma unroll
    for(int k=0;k<4;k++) s += mu[b*4+k];
    for(int l=0;l<L_;l++){
      const float* p = inc + (b*L_+l)*4;
      s += p[0]+p[1]+p[2]+p[3];
    }
    out[b] = s * 0.25f;
  }
}

// ---------------- launch ----------------
extern "C" void kernel_launch(void* const* d_in, const int* in_sizes, int n_in,
                              void* d_out, int out_size, void* d_ws, size_t ws_size,
                              hipStream_t stream){
  const float* embed = (const float*)d_in[0];
  const float* delta = (const float*)d_in[1];
  const float* tau_p = (const float*)d_in[2];
  const float* W1    = (const float*)d_in[3];
  const float* W2    = (const float*)d_in[4];
  const float* seqs_time = (const float*)d_in[5];
  const float* clk_time  = (const float*)d_in[6];
  const int* uid      = (const int*)d_in[7];
  const int* sid      = (const int*)d_in[8];
  const int* node_ids = (const int*)d_in[9];
  const int* edge_index = (const int*)d_in[10];
  const int* seq_map  = (const int*)d_in[11];
  const int* tar_map  = (const int*)d_in[12];
  const int* seq_idx  = (const int*)d_in[13];
  const int* seq_len  = (const int*)d_in[14];
  const int* row = edge_index;
  const int* col = edge_index + E_;
  float* out = (float*)d_out;

  // carve: ONE contiguous zero-init region first (inc,ncount,cnt,need,markpos)
  char* wp = (char*)d_ws;
  size_t o = 0;
  auto carve = [&](size_t bytes)->char*{ char* r = wp + o; o = (o + bytes + 255) & ~(size_t)255; return r; };
  float* inc     = (float*)carve((size_t)B_*L_*4*4);   // 102 KB, zeroed each call
  int*   ncount  = (int*)  carve((size_t)4);
  int*   cnt     = (int*)  carve((size_t)NT_*4);
  int*   need    = (int*)  carve((size_t)NT_*4);
  int*   markpos = (int*)  carve((size_t)NT_*4);
  char*  zero_end = wp + o;
  float* mu      = (float*)carve((size_t)B_*4*4);
  float* sc      = (float*)carve((size_t)B_*4*2*4);
  float* a_v     = (float*)carve((size_t)B_*KD_*4);
  int*   nlist   = (int*)  carve((size_t)MAXN_*4);
  float* W1T     = (float*)carve((size_t)64*64*4);
  float* W2T     = (float*)carve((size_t)64*64*4);
  int2*  pk2     = (int2*) carve((size_t)NT_*CAP_*8);   // ~24.6 MB slot CSR
  float* wgt     = (float*)carve((size_t)NT_*CAP_*4);   // ~12.3 MB prefolded weights
  float* x2c     = (float*)carve((size_t)MAXN_*KD_*4);
  float* x1      = (float*)carve((size_t)NT_*KD_*4);    // 64 MB

  hipMemsetAsync(inc, 0, (size_t)(zero_end - (char*)inc), stream);

  // K1: head-node dedup + slot-CSR fill (one pass over E)
  fill_all<<<(E_+255)/256, 256, 0, stream>>>(seq_map, tar_map, row, col, node_ids,
                                             markpos, nlist, ncount, need, cnt, pk2);
  // K2: need propagation + W transposes + prefolded edge weights
  prep_all<<<(MAXN_+255)/256 + 32 + NT_/256, 256, 0, stream>>>(cnt, pk2, nlist, ncount,
                                                               W1, W2, need, W1T, W2T, wgt);
  // K3: conv1, only for nodes whose x1 is read downstream
  aggregate1<<<NT_/4, 256, 0, stream>>>((const float4*)embed, cnt, pk2, wgt,
                                        need, (float4*)x1);
  // K4: conv2
  conv2_fused<<<MAXN_, 256, 0, stream>>>(x1, cnt, pk2, wgt, nlist, ncount, x2c);
  // K5: per-b a_v matvec + norms + mu
  prep_av<<<B_, 256, 0, stream>>>(embed, x2c, markpos, W2T, uid, sid, tar_map,
                                  a_v, mu, sc);
  // K6: head (se matvec only)
  head_fused<<<B_*L_, 256, 0, stream>>>(embed, x2c, markpos, a_v, sc, W1T,
                                        node_ids, seq_map, seq_idx, seq_len, uid,
                                        seqs_time, clk_time, tau_p, delta, inc);
  // K7: finalize
  finalize<<<1, 128, 0, stream>>>(mu, inc, out);
}

// Round 23
// 131.303 us; speedup vs baseline: 1.6224x; 1.0492x over previous
//
#include <hip/hip_runtime.h>
#include <math.h>

// Problem constants (match reference)
#define NT_     64000
#define E_      400000
#define B_      128
#define L_      50
#define KD_     256     // K*D
#define D_      64
#define N_USER_ 100000
#define MAXN_   (B_*L_ + B_)   // 6528 max distinct head nodes
#define CAP_    48             // per-node slot capacity; P(Poisson(6.25) > 48) ~ 1e-30

// ---------------- wave helpers ----------------
__device__ __forceinline__ float wred(float v){
#pragma unroll
  for(int s=32;s;s>>=1) v += __shfl_xor(v, s, 64);
  return v;
}

// ---------------- threefry2x32 (JAX key(1) == (0,1)), partitionable XOR-fold ----------------
__device__ __forceinline__ unsigned rotl(unsigned x, int r){ return (x<<r)|(x>>(32-r)); }

__device__ void tf2x32(unsigned c0, unsigned c1, unsigned &o0, unsigned &o1){
  const unsigned k0=0u, k1=1u;
  const unsigned k2=k0^k1^0x1BD11BDAu;
  unsigned x0=c0+k0, x1=c1+k1;
  const int RA[4]={13,15,26,6};
  const int RB[4]={17,29,16,24};
#pragma unroll
  for(int i=0;i<4;i++){ x0+=x1; x1=rotl(x1,RA[i]); x1^=x0; }
  x0+=k1; x1+=k2+1u;
#pragma unroll
  for(int i=0;i<4;i++){ x0+=x1; x1=rotl(x1,RB[i]); x1^=x0; }
  x0+=k2; x1+=k0+2u;
#pragma unroll
  for(int i=0;i<4;i++){ x0+=x1; x1=rotl(x1,RA[i]); x1^=x0; }
  x0+=k0; x1+=k1+3u;
#pragma unroll
  for(int i=0;i<4;i++){ x0+=x1; x1=rotl(x1,RB[i]); x1^=x0; }
  x0+=k1; x1+=k2+4u;
#pragma unroll
  for(int i=0;i<4;i++){ x0+=x1; x1=rotl(x1,RA[i]); x1^=x0; }
  x0+=k2; x1+=k0+5u;
  o0=x0; o1=x1;
}

__device__ float gumbel_at(int idx){
  unsigned o0,o1;
  tf2x32(0u, (unsigned)idx, o0, o1);      // counts uint64 iota: hi=0, lo=idx
  unsigned bits = o0 ^ o1;                 // 32-bit XOR fold (partitionable)
  unsigned fb = (bits>>9) | 0x3f800000u;   // [1,2)
  float f = __uint_as_float(fb) - 1.0f;    // [0,1)
  const float mn=1e-4f, mx=1.0f-1e-4f;
  float u = fmaxf(mn, f*(mx-mn)+mn);
  return -logf(-logf(u));
}

// ---------------- K1: head-node dedup + slot-CSR fill (single pass over E) ----------------
// markpos encoding: 0 = unassigned, s+1 = slot s (zero-memset friendly)
__global__ void fill_all(const int* __restrict__ seq_map, const int* __restrict__ tar_map,
                         const int* __restrict__ row, const int* __restrict__ col,
                         const int* __restrict__ node_ids,
                         int* __restrict__ markpos, int* __restrict__ nlist,
                         int* __restrict__ ncount, int* __restrict__ need,
                         int* __restrict__ cnt, int2* __restrict__ pk2){
  int i = blockIdx.x*256 + threadIdx.x;
  if(i < MAXN_){
    int n = (i < B_*L_) ? seq_map[i] : tar_map[i - B_*L_];
    int old = atomicCAS(&markpos[n], 0, -1);
    if(old == 0){
      int s = atomicAdd(ncount, 1);
      nlist[s] = n;
      need[n] = 1;
      markpos[n] = s + 1;
    }
  }
  if(i < E_){
    int c = col[i], r = row[i];
    int j = atomicAdd(&cnt[c], 1);
    if(j < CAP_) pk2[c*CAP_ + j] = make_int2(node_ids[r], r);
  }
}

// ---------------- K2: prep — need prop + W transposes + prefolded edge weights ----------------
__global__ void prep_all(const int* __restrict__ cnt, const int2* __restrict__ pk2,
                         const int* __restrict__ nlist, const int* __restrict__ ncount,
                         const float* __restrict__ W1, const float* __restrict__ W2,
                         int* __restrict__ need, float* __restrict__ W1T,
                         float* __restrict__ W2T, float* __restrict__ wgt){
  const int NB_NEED = (MAXN_+255)/256;    // 26
  int b = blockIdx.x, t = threadIdx.x;
  if(b < NB_NEED){
    int s = b*256 + t;
    if(s < *ncount){
      int c = nlist[s];
      int d = cnt[c]; if(d > CAP_) d = CAP_;
      int base = c*CAP_;
      for(int j=0;j<d;j++) need[pk2[base+j].y] = 1;   // x1[r] read by conv2
    }
  } else if(b < NB_NEED + 32){
    int tb = b - NB_NEED;
    int idx = (tb & 15)*256 + t;         // 0..4095
    int e = idx >> 6, d = idx & 63;
    if(tb < 16) W1T[d*64 + e] = W1[e*64 + d];
    else        W2T[d*64 + e] = W2[e*64 + d];
  } else {
    int c = (b - NB_NEED - 32)*256 + t;  // one thread per node
    int d = cnt[c]; if(d > CAP_) d = CAP_;
    if(d > 0){
      float dc = (1.0f/sqrtf((float)cnt[c]))*0.25f;
      int base = c*CAP_;
      for(int j=0;j<d;j++){
        int r = pk2[base+j].y;
        int cr = cnt[r];
        float dr = (cr>0) ? (1.0f/sqrtf((float)cr)) : 0.0f;
        wgt[base+j] = dr*dc;
      }
    }
  }
}

// ---------------- K3: conv1 (filtered): wave-per-node, sequential pk2/wgt streams ----------------
__global__ void aggregate1(const float4* __restrict__ embed4, const int* __restrict__ cnt,
                           const int2* __restrict__ pk2, const float* __restrict__ wgt,
                           const int* __restrict__ need, float4* __restrict__ x14){
  int wv = threadIdx.x>>6, lane = threadIdx.x&63;
  int c = blockIdx.x*4 + wv;
  if(!need[c]) return;                    // x1[c] never read downstream
  int deg = cnt[c]; if(deg > CAP_) deg = CAP_;
  int base = c*CAP_;
  float4 acc = {0.f,0.f,0.f,0.f};
  for(int i=0; i<deg; i+=8){
    int idx[8]; float w[8];
#pragma unroll
    for(int j=0;j<8;j++){
      bool ok = (i+j) < deg;
      int s = ok ? (base+i+j) : base;
      idx[j] = pk2[s].x;
      w[j]   = ok ? wgt[s] : 0.f;
    }
#pragma unroll
    for(int j=0;j<8;j++){
      float4 v = embed4[(size_t)idx[j]*64 + lane];
      acc.x = fmaf(v.x, w[j], acc.x);
      acc.y = fmaf(v.y, w[j], acc.y);
      acc.z = fmaf(v.z, w[j], acc.z);
      acc.w = fmaf(v.w, w[j], acc.w);
    }
  }
  x14[(size_t)c*64+lane] = acc;
}

// ---------------- K4: conv2 fused — UNROLLED independent wred chains (ILP) ----------------
__global__ void conv2_fused(const float* __restrict__ x1, const int* __restrict__ cnt,
                            const int2* __restrict__ pk2, const float* __restrict__ wgt,
                            const int* __restrict__ nlist, const int* __restrict__ ncount,
                            float* __restrict__ x2c){
  int slot = blockIdx.x;
  if(slot >= *ncount) return;
  int c = nlist[slot];
  int t = threadIdx.x, k = t>>6, lane = t&63;
  float tx = tanhf(x1[(size_t)c*KD_ + t]);
  float acc = 0.f;
  __shared__ float zs[8][4];
  __shared__ float ws[8][4];
  int deg = cnt[c]; if(deg > CAP_) deg = CAP_;
  int base = c*CAP_;
  for(int i0=0; i0<deg; i0+=8){
    int nb = deg - i0; nb = (nb>8)?8:nb;  // block-uniform
    float xr8[8];
    // P1a: loads (zero-fill inactive so unconditional math below is safe)
#pragma unroll
    for(int j=0;j<8;j++)
      xr8[j] = (j<nb) ? x1[(size_t)pk2[base+i0+j].y*KD_ + t] : 0.f;
    // P1b: 8 INDEPENDENT wred chains, fully unrolled -> scheduler interleaves them
    float zk8[8];
#pragma unroll
    for(int j=0;j<8;j++)
      zk8[j] = wred(xr8[j]*tx);
    if(lane==0){
#pragma unroll
      for(int j=0;j<8;j++)
        if(j<nb) zs[j][k] = zk8[j];
    }
    __syncthreads();
    // P1.5: thread j (< nb) computes edge j's softmax ONCE -> ws[j][*]
    if(t < nb){
      float z0=zs[t][0], z1=zs[t][1], z2=zs[t][2], z3=zs[t][3];
      float m = fmaxf(fmaxf(z0,z1), fmaxf(z2,z3));
      float e0=expf(z0-m), e1=expf(z1-m), e2=expf(z2-m), e3=expf(z3-m);
      float inv = (4.f*wgt[base+i0+t])/(e0+e1+e2+e3);   // base_e = 4*wgt
      ws[t][0]=e0*inv; ws[t][1]=e1*inv; ws[t][2]=e2*inv; ws[t][3]=e3*inv;
    }
    __syncthreads();
    // P2: accumulate
    for(int j=0;j<nb;j++)
      acc = fmaf(xr8[j], ws[j][k], acc);
  }
  x2c[(size_t)slot*KD_ + t] = acc;
}

// ---------------- K5: prep_av — per-b a_v matvec + norms + mu ----------------
__global__ void prep_av(const float* __restrict__ embed, const float* __restrict__ x2c,
                        const int* __restrict__ markpos, const float* __restrict__ W2T,
                        const int* __restrict__ uid, const int* __restrict__ sid,
                        const int* __restrict__ tar_map,
                        float* __restrict__ a_v, float* __restrict__ mu,
                        float* __restrict__ sc){
  int b = blockIdx.x;
  int t = threadIdx.x, k = t>>6, lane = t&63;
  __shared__ float sxt[KD_];
  sxt[t] = x2c[(size_t)(markpos[tar_map[b]]-1)*KD_ + t];
  __syncthreads();
  float av = embed[((size_t)(N_USER_ + sid[b]))*KD_ + t];
  const float* xt_k = sxt + k*64;
#pragma unroll 8
  for(int d=0; d<64; d++)
    av = fmaf(xt_k[d], W2T[d*64 + lane], av);
  float au = embed[(size_t)uid[b]*KD_ + t];
  float nv  = wred(av*av);
  float nu  = wred(au*au);
  float duv = wred(av*au);
  a_v[(size_t)b*KD_ + t] = av;
  if(lane==0){
    float rnv = fmaxf(sqrtf(nv), 1e-8f);
    float rnu = fmaxf(sqrtf(nu), 1e-8f);
    mu[b*4+k]      = duv/(rnv*rnu);
    sc[(b*4+k)*2+0] = 1.f/rnv;
    sc[(b*4+k)*2+1] = 1.f/rnu;
  }
}

// ---------------- K6: head — se matvec only; av/scalars precomputed ----------------
__global__ void head_fused(const float* __restrict__ embed, const float* __restrict__ x2c,
                           const int* __restrict__ markpos, const float* __restrict__ a_v,
                           const float* __restrict__ sc, const float* __restrict__ W1T,
                           const int* __restrict__ node_ids, const int* __restrict__ seq_map,
                           const int* __restrict__ seq_idx, const int* __restrict__ seq_len,
                           const int* __restrict__ uid,
                           const float* __restrict__ seqs_time, const float* __restrict__ clk_time,
                           const float* __restrict__ tau_p, const float* __restrict__ delta,
                           float* __restrict__ inc){
  int bl = blockIdx.x;
  int b = bl / L_, l = bl % L_;
  if(l >= seq_len[b]) return;           // masked position: inc stays 0 (memset)
  int t = threadIdx.x, k = t>>6, lane = t&63;
  __shared__ float sxv[KD_];
  int n = seq_map[bl];
  sxv[t] = x2c[(size_t)(markpos[n]-1)*KD_ + t];
  __syncthreads();
  float se = embed[(size_t)node_ids[n]*KD_ + t];
  const float* xv_k = sxv + k*64;
#pragma unroll 8
  for(int d=0; d<64; d++)
    se = fmaf(xv_k[d], W1T[d*64 + lane], se);
  float av = a_v[(size_t)b*KD_ + t];
  float au = embed[(size_t)uid[b]*KD_ + t];
  float dv  = wred(se*av);
  float du  = wred(se*au);
  float ns  = wred(se*se);
  __shared__ float s3[3][4];
  if(lane==0){ s3[0][k]=dv; s3[1][k]=du; s3[2][k]=ns; }
  __syncthreads();
  if(t==0){
    float jv  = expf(-(clk_time[b]-seqs_time[bl]) * (1.0f/1000.0f) * delta[uid[b]]);
    float tau = tau_p[seq_idx[bl]];
    float gam[4], lg[4];
    float m = -1e30f;
#pragma unroll
    for(int kk=0;kk<4;kk++){
      float ins = 1.f/fmaxf(sqrtf(s3[2][kk]), 1e-8f);
      gam[kk] = s3[0][kk]*ins*sc[(b*4+kk)*2+0];
      float logit = s3[1][kk]*ins*sc[(b*4+kk)*2+1];
      lg[kk] = (logit + gumbel_at(bl*4+kk))/tau;
      m = fmaxf(m, lg[kk]);
    }
    float es[4], ssum=0.f;
#pragma unroll
    for(int kk=0;kk<4;kk++){ es[kk]=expf(lg[kk]-m); ssum+=es[kk]; }
    float isum = 1.f/ssum;
#pragma unroll
    for(int kk=0;kk<4;kk++)
      inc[bl*4+kk] = jv * gam[kk] * es[kk]*isum;   // direct write (idempotent)
  }
}

// ---------------- K7: finalize — sums inc over l ----------------
__global__ void finalize(const float* __restrict__ mu, const float* __restrict__ inc,
                         float* __restrict__ out){
  int b = threadIdx.x;
  if(b < B_){
    float s = 0.f;
#pragma unroll
    for(int k=0;k<4;k++) s += mu[b*4+k];
    for(int l=0;l<L_;l++){
      const float* p = inc + (b*L_+l)*4;
      s += p[0]+p[1]+p[2]+p[3];
    }
    out[b] = s * 0.25f;
  }
}

// ---------------- launch ----------------
extern "C" void kernel_launch(void* const* d_in, const int* in_sizes, int n_in,
                              void* d_out, int out_size, void* d_ws, size_t ws_size,
                              hipStream_t stream){
  const float* embed = (const float*)d_in[0];
  const float* delta = (const float*)d_in[1];
  const float* tau_p = (const float*)d_in[2];
  const float* W1    = (const float*)d_in[3];
  const float* W2    = (const float*)d_in[4];
  const float* seqs_time = (const float*)d_in[5];
  const float* clk_time  = (const float*)d_in[6];
  const int* uid      = (const int*)d_in[7];
  const int* sid      = (const int*)d_in[8];
  const int* node_ids = (const int*)d_in[9];
  const int* edge_index = (const int*)d_in[10];
  const int* seq_map  = (const int*)d_in[11];
  const int* tar_map  = (const int*)d_in[12];
  const int* seq_idx  = (const int*)d_in[13];
  const int* seq_len  = (const int*)d_in[14];
  const int* row = edge_index;
  const int* col = edge_index + E_;
  float* out = (float*)d_out;

  // carve: ONE contiguous zero-init region first (inc,ncount,cnt,need,markpos)
  char* wp = (char*)d_ws;
  size_t o = 0;
  auto carve = [&](size_t bytes)->char*{ char* r = wp + o; o = (o + bytes + 255) & ~(size_t)255; return r; };
  float* inc     = (float*)carve((size_t)B_*L_*4*4);   // 102 KB, zeroed each call
  int*   ncount  = (int*)  carve((size_t)4);
  int*   cnt     = (int*)  carve((size_t)NT_*4);
  int*   need    = (int*)  carve((size_t)NT_*4);
  int*   markpos = (int*)  carve((size_t)NT_*4);
  char*  zero_end = wp + o;
  float* mu      = (float*)carve((size_t)B_*4*4);
  float* sc      = (float*)carve((size_t)B_*4*2*4);
  float* a_v     = (float*)carve((size_t)B_*KD_*4);
  int*   nlist   = (int*)  carve((size_t)MAXN_*4);
  float* W1T     = (float*)carve((size_t)64*64*4);
  float* W2T     = (float*)carve((size_t)64*64*4);
  int2*  pk2     = (int2*) carve((size_t)NT_*CAP_*8);   // ~24.6 MB slot CSR
  float* wgt     = (float*)carve((size_t)NT_*CAP_*4);   // ~12.3 MB prefolded weights
  float* x2c     = (float*)carve((size_t)MAXN_*KD_*4);
  float* x1      = (float*)carve((size_t)NT_*KD_*4);    // 64 MB

  hipMemsetAsync(inc, 0, (size_t)(zero_end - (char*)inc), stream);

  // K1: head-node dedup + slot-CSR fill (one pass over E)
  fill_all<<<(E_+255)/256, 256, 0, stream>>>(seq_map, tar_map, row, col, node_ids,
                                             markpos, nlist, ncount, need, cnt, pk2);
  // K2: need propagation + W transposes + prefolded edge weights
  prep_all<<<(MAXN_+255)/256 + 32 + NT_/256, 256, 0, stream>>>(cnt, pk2, nlist, ncount,
                                                               W1, W2, need, W1T, W2T, wgt);
  // K3: conv1, only for nodes whose x1 is read downstream
  aggregate1<<<NT_/4, 256, 0, stream>>>((const float4*)embed, cnt, pk2, wgt,
                                        need, (float4*)x1);
  // K4: conv2 (unrolled independent wred chains)
  conv2_fused<<<MAXN_, 256, 0, stream>>>(x1, cnt, pk2, wgt, nlist, ncount, x2c);
  // K5: per-b a_v matvec + norms + mu
  prep_av<<<B_, 256, 0, stream>>>(embed, x2c, markpos, W2T, uid, sid, tar_map,
                                  a_v, mu, sc);
  // K6: head (se matvec only)
  head_fused<<<B_*L_, 256, 0, stream>>>(embed, x2c, markpos, a_v, sc, W1T,
                                        node_ids, seq_map, seq_idx, seq_len, uid,
                                        seqs_time, clk_time, tau_p, delta, inc);
  // K7: finalize
  finalize<<<1, 128, 0, stream>>>(mu, inc, out);
}